// Round 1
// baseline (658.587 us; speedup 1.0000x reference)
//
#include <hip/hip_runtime.h>
#include <hip/hip_bf16.h>

#define BATCH   8192
#define IN_SZ   1024
#define HSZ     2048
#define GG      1024
#define KTOT    2048

typedef __hip_bfloat16 bf16;
typedef __attribute__((ext_vector_type(8))) short  short8;
typedef __attribute__((ext_vector_type(4))) float  floatx4;

typedef __attribute__((address_space(1))) const void gvoid_t;
typedef __attribute__((address_space(3))) void       lvoid_t;

__device__ __forceinline__ void async_ld16(void* lds, const void* g) {
  __builtin_amdgcn_global_load_lds((gvoid_t*)g, (lvoid_t*)lds, 16, 0, 0);
}

// ---------------- prep: cast x -> bf16, h2 -> bf16 float, zero bits acc ----
__global__ void prep_kernel(const float* __restrict__ x, bf16* __restrict__ xb,
                            const int* __restrict__ hidden, bf16* __restrict__ hf,
                            float* accp) {
  int idx = blockIdx.x * blockDim.x + threadIdx.x;     // 0 .. 8192*1024/4-1
  int i = idx * 4;
  float4 xv = *(const float4*)(x + i);
  xb[i + 0] = __float2bfloat16(xv.x);
  xb[i + 1] = __float2bfloat16(xv.y);
  xb[i + 2] = __float2bfloat16(xv.z);
  xb[i + 3] = __float2bfloat16(xv.w);
  int m = i >> 10, j = i & 1023;
  int4 hv = *(const int4*)(hidden + m * HSZ + GG + j);
  const float sc = 1.0f / 8388608.0f;   // 2^-23
  hf[i + 0] = __float2bfloat16((float)hv.x * sc);
  hf[i + 1] = __float2bfloat16((float)hv.y * sc);
  hf[i + 2] = __float2bfloat16((float)hv.z * sc);
  hf[i + 3] = __float2bfloat16((float)hv.w * sc);
  if (idx == 0) *accp = 0.0f;
}

// ---------------- weight transpose + cast:  W (K x N, f32) -> Wt (N x K, bf16)
__global__ void transpose_cast(const float* __restrict__ W, bf16* __restrict__ Wt,
                               int K, int N) {
  __shared__ float tile[32][33];
  int bx = blockIdx.x, by = blockIdx.y;     // bx: n-tile, by: k-tile
  int tx = threadIdx.x, ty = threadIdx.y;   // (32, 8)
  int n_in = bx * 32 + tx;
  int k_in = by * 32 + ty;
#pragma unroll
  for (int s = 0; s < 32; s += 8)
    tile[ty + s][tx] = W[(size_t)(k_in + s) * N + n_in];
  __syncthreads();
  int n_out = bx * 32 + ty;
  int k_out = by * 32 + tx;
#pragma unroll
  for (int s = 0; s < 32; s += 8)
    Wt[(size_t)(n_out + s) * K + k_out] = __float2bfloat16(tile[tx][ty + s]);
}

// ---------------- shared GEMM mainloop: C(128x128) += [Aleft|Aright] @ Bt^T --
// Aleft/Aright: row-major M x 1024 bf16.  Bt: row-major N x 2048 bf16.
__device__ __forceinline__ void gemm_mainloop(const bf16* __restrict__ Aleft,
                                              const bf16* __restrict__ Aright,
                                              const bf16* __restrict__ Bt,
                                              bf16* As, bf16* Bs,
                                              int m0, int n0, floatx4 acc[4][4]) {
  int t = threadIdx.x;
  int r = t >> 2, c = t & 3;
  int lane = t & 63;
  int q = lane >> 4, r16 = lane & 15;
  int w = t >> 6;
  int wm = w & 1, wn = w >> 1;

  const size_t arow0 = (size_t)(m0 + r) * IN_SZ;
  const size_t arow1 = (size_t)(m0 + r + 64) * IN_SZ;
  const size_t brow0 = (size_t)(n0 + r) * KTOT;
  const size_t brow1 = (size_t)(n0 + r + 64) * KTOT;
  bf16* lA0 = As + t * 8;
  bf16* lA1 = As + 64 * 32 + t * 8;
  bf16* lB0 = Bs + t * 8;
  bf16* lB1 = Bs + 64 * 32 + t * 8;
  const bf16* aRd = As + (wm * 64 + r16) * 32 + q * 8;
  const bf16* bRd = Bs + (wn * 64 + r16) * 32 + q * 8;

  for (int kb = 0; kb < KTOT / 32; ++kb) {
    int kt = kb * 32;
    const bf16* asrc; int kloc;
    if (kt < IN_SZ) { asrc = Aleft;  kloc = kt; }
    else            { asrc = Aright; kloc = kt - IN_SZ; }
    int ac = kloc + c * 8;
    async_ld16(lA0, asrc + arow0 + ac);
    async_ld16(lA1, asrc + arow1 + ac);
    int bc = kt + c * 8;
    async_ld16(lB0, Bt + brow0 + bc);
    async_ld16(lB1, Bt + brow1 + bc);
    __syncthreads();                       // drains vmcnt before LDS reads
    short8 af[4], bfr[4];
#pragma unroll
    for (int i = 0; i < 4; ++i) af[i]  = *(const short8*)(const void*)(aRd + i * 16 * 32);
#pragma unroll
    for (int j = 0; j < 4; ++j) bfr[j] = *(const short8*)(const void*)(bRd + j * 16 * 32);
#pragma unroll
    for (int i = 0; i < 4; ++i)
#pragma unroll
      for (int j = 0; j < 4; ++j)
        acc[i][j] = __builtin_amdgcn_mfma_f32_16x16x32_bf16(af[i], bfr[j], acc[i][j], 0, 0, 0);
    __syncthreads();                       // protect LDS overwrite next iter
  }
}

// ---------------- zr stage: sigmoid; z-cols -> zbuf + bits; r-cols -> r*h ---
__global__ void gemm_zr(const bf16* __restrict__ xb, const bf16* __restrict__ hfp,
                        const bf16* __restrict__ Bt, const float* __restrict__ bias,
                        float* __restrict__ zbuf, bf16* __restrict__ rh,
                        const int* __restrict__ slice_ptr, int use_slice,
                        float* __restrict__ accp) {
  __shared__ bf16 As[128 * 32];
  __shared__ bf16 Bs[128 * 32];
  floatx4 acc[4][4];
#pragma unroll
  for (int i = 0; i < 4; ++i)
#pragma unroll
    for (int j = 0; j < 4; ++j) acc[i][j] = (floatx4)0.0f;

  int m0 = blockIdx.y * 128, n0 = blockIdx.x * 128;
  gemm_mainloop(xb, hfp, Bt, As, Bs, m0, n0, acc);

  int t = threadIdx.x;
  int lane = t & 63, q = lane >> 4, r16 = lane & 15;
  int w = t >> 6, wm = w & 1, wn = w >> 1;
  int nmin = use_slice ? *slice_ptr : 0;
  float lsum = 0.0f;

#pragma unroll
  for (int i = 0; i < 4; ++i) {
    int mbase = m0 + wm * 64 + i * 16 + q * 4;
#pragma unroll
    for (int j = 0; j < 4; ++j) {
      int n = n0 + wn * 64 + j * 16 + r16;
      float bn = bias[n];
#pragma unroll
      for (int rr = 0; rr < 4; ++rr) {
        int m = mbase + rr;
        float v = acc[i][j][rr] + bn;
        float s = 1.0f / (1.0f + __expf(-v));
        if (n < GG) {
          float z = 0.875f * s + 0.125f;
          zbuf[(size_t)m * GG + n] = z;
          if (n >= nmin) lsum += -__log2f(z);
        } else {
          int jc = n - GG;
          float hfl = __bfloat162float(hfp[(size_t)m * GG + jc]);
          rh[(size_t)m * GG + jc] = __float2bfloat16(s * hfl);
        }
      }
    }
  }
  // block-level reduction of -log2(z) sum, one atomic per block
  __syncthreads();
  float* sf = (float*)As;
#pragma unroll
  for (int off = 32; off > 0; off >>= 1) lsum += __shfl_down(lsum, off, 64);
  if (lane == 0) sf[w] = lsum;
  __syncthreads();
  if (t == 0) atomicAdd(accp, sf[0] + sf[1] + sf[2] + sf[3]);
}

// ---------------- g stage: tanh + fixed-point hidden update + outputs -------
__global__ void gemm_g(const bf16* __restrict__ xb, const bf16* __restrict__ rh,
                       const bf16* __restrict__ Bt, const float* __restrict__ bias,
                       const float* __restrict__ zbuf, const int* __restrict__ hidden,
                       int col_off,
                       float* __restrict__ out0, float* __restrict__ out1,
                       bf16* __restrict__ hf_out, int write_hf,
                       int write_bits, const float* __restrict__ accp,
                       const int* __restrict__ slice_ptr, float* __restrict__ out2) {
  __shared__ bf16 As[128 * 32];
  __shared__ bf16 Bs[128 * 32];
  floatx4 acc[4][4];
#pragma unroll
  for (int i = 0; i < 4; ++i)
#pragma unroll
    for (int j = 0; j < 4; ++j) acc[i][j] = (floatx4)0.0f;

  int m0 = blockIdx.y * 128, n0 = blockIdx.x * 128;
  gemm_mainloop(xb, rh, Bt, As, Bs, m0, n0, acc);

  int t = threadIdx.x;
  int lane = t & 63, q = lane >> 4, r16 = lane & 15;
  int w = t >> 6, wm = w & 1, wn = w >> 1;

#pragma unroll
  for (int i = 0; i < 4; ++i) {
    int mbase = m0 + wm * 64 + i * 16 + q * 4;
#pragma unroll
    for (int j = 0; j < 4; ++j) {
      int n = n0 + wn * 64 + j * 16 + r16;
      float bn = bias[n];
#pragma unroll
      for (int rr = 0; rr < 4; ++rr) {
        int m = mbase + rr;
        float v = acc[i][j][rr] + bn;
        float e = __expf(2.0f * v);
        float g = 1.0f - 2.0f / (e + 1.0f);          // tanh(v)
        float z = zbuf[(size_t)m * GG + n];
        int zfix = (int)(z * 1024.0f);               // trunc (z > 0)
        if (zfix < 1) zfix = 1;
        long long h = hidden[(size_t)m * HSZ + col_off + n];
        long long hupd = (h * (long long)zfix) >> 10;      // floor div 2^10
        float t2 = (1.0f - z) * g * 8388608.0f;            // *2^23
        long long f2 = (long long)t2;                      // trunc toward zero
        int hnew = (int)(hupd + f2);
        size_t oidx = (size_t)m * HSZ + col_off + n;
        out0[oidx] = (float)hnew;
        float ofl = (float)hnew * (1.0f / 8388608.0f);
        out1[oidx] = ofl;
        if (write_hf) hf_out[(size_t)m * GG + n] = __float2bfloat16(ofl);
      }
    }
  }
  if (write_bits && blockIdx.x == 0 && blockIdx.y == 0 && t == 0) {
    *out2 = *accp + 32.0f * (float)(*slice_ptr) * (float)BATCH;
  }
}

extern "C" void kernel_launch(void* const* d_in, const int* in_sizes, int n_in,
                              void* d_out, int out_size, void* d_ws, size_t ws_size,
                              hipStream_t stream) {
  const float* x      = (const float*)d_in[0];
  const int*   hidden = (const int*)d_in[1];
  const float* W_zr1  = (const float*)d_in[2];
  const float* b_zr1  = (const float*)d_in[3];
  const float* W_g1   = (const float*)d_in[4];
  const float* b_g1   = (const float*)d_in[5];
  const float* W_zr2  = (const float*)d_in[6];
  const float* b_zr2  = (const float*)d_in[7];
  const float* W_g2   = (const float*)d_in[8];
  const float* b_g2   = (const float*)d_in[9];
  const int*   slice  = (const int*)d_in[10];

  char* ws = (char*)d_ws;
  size_t off = 0;
  auto alloc = [&](size_t bytes) -> void* {
    void* p = ws + off;
    off += (bytes + 255) & ~(size_t)255;
    return p;
  };
  bf16* xb     = (bf16*)alloc((size_t)BATCH * IN_SZ * 2);
  bf16* wt_zr1 = (bf16*)alloc((size_t)2048 * 2048 * 2);
  bf16* wt_g1  = (bf16*)alloc((size_t)1024 * 2048 * 2);
  bf16* wt_zr2 = (bf16*)alloc((size_t)2048 * 2048 * 2);
  bf16* wt_g2  = (bf16*)alloc((size_t)1024 * 2048 * 2);
  bf16* hf     = (bf16*)alloc((size_t)BATCH * GG * 2);
  bf16* rh     = (bf16*)alloc((size_t)BATCH * GG * 2);
  float* zbuf  = (float*)alloc((size_t)BATCH * GG * 4);
  float* accp  = (float*)alloc(256);

  float* out0 = (float*)d_out;
  float* out1 = out0 + (size_t)BATCH * HSZ;
  float* out2 = out0 + 2 * (size_t)BATCH * HSZ;

  prep_kernel<<<BATCH * IN_SZ / 4 / 256, 256, 0, stream>>>(x, xb, hidden, hf, accp);
  transpose_cast<<<dim3(64, 64), dim3(32, 8), 0, stream>>>(W_zr1, wt_zr1, 2048, 2048);
  transpose_cast<<<dim3(32, 64), dim3(32, 8), 0, stream>>>(W_g1,  wt_g1,  2048, 1024);
  transpose_cast<<<dim3(64, 64), dim3(32, 8), 0, stream>>>(W_zr2, wt_zr2, 2048, 2048);
  transpose_cast<<<dim3(32, 64), dim3(32, 8), 0, stream>>>(W_g2,  wt_g2,  2048, 1024);

  // stage 1: zr1 = sigmoid([x|h2f] @ W_zr1 + b)
  gemm_zr<<<dim3(16, 64), 256, 0, stream>>>(xb, hf, wt_zr1, b_zr1, zbuf, rh, slice, 1, accp);
  // stage 2: g1 = tanh([x|r1*h2f] @ W_g1 + b); h1 update; writes h1_fl into hf
  gemm_g<<<dim3(8, 64), 256, 0, stream>>>(xb, rh, wt_g1, b_g1, zbuf, hidden, 0,
                                          out0, out1, hf, 1, 0, accp, slice, out2);
  // stage 3: zr2 = sigmoid([x|h1f] @ W_zr2 + b)
  gemm_zr<<<dim3(16, 64), 256, 0, stream>>>(xb, hf, wt_zr2, b_zr2, zbuf, rh, slice, 0, accp);
  // stage 4: g2 = tanh([x|r2*h1f] @ W_g2 + b); h2 update; writes optimal_bits
  gemm_g<<<dim3(8, 64), 256, 0, stream>>>(xb, rh, wt_g2, b_g2, zbuf, hidden, 1024,
                                          out0, out1, hf, 0, 1, accp, slice, out2);
}

// Round 2
// 644.298 us; speedup vs baseline: 1.0222x; 1.0222x over previous
//
#include <hip/hip_runtime.h>
#include <hip/hip_bf16.h>

#define BATCH   8192
#define IN_SZ   1024
#define HSZ     2048
#define GG      1024
#define KTOT    2048

typedef __hip_bfloat16 bf16;
typedef __attribute__((ext_vector_type(8))) short  short8;
typedef __attribute__((ext_vector_type(4))) float  floatx4;

typedef __attribute__((address_space(1))) const void gvoid_t;
typedef __attribute__((address_space(3))) void       lvoid_t;

__device__ __forceinline__ void async_ld16(void* lds, const void* g) {
  __builtin_amdgcn_global_load_lds((gvoid_t*)g, (lvoid_t*)lds, 16, 0, 0);
}

// ---------------- fused prep: x->bf16, h2->bf16 float, 4 weight transposes --
// blocks [0,3072): weight transpose+cast tiles (64x64)
// blocks [3072,11264): x / h2 cast
__global__ void prep_all(const float* __restrict__ x, bf16* __restrict__ xb,
                         const int* __restrict__ hidden, bf16* __restrict__ hf,
                         float* accp,
                         const float* __restrict__ W_zr1, const float* __restrict__ W_g1,
                         const float* __restrict__ W_zr2, const float* __restrict__ W_g2,
                         bf16* __restrict__ wt_zr1, bf16* __restrict__ wt_g1,
                         bf16* __restrict__ wt_zr2, bf16* __restrict__ wt_g2) {
  int b = blockIdx.x;
  int t = threadIdx.x;
  if (b < 3072) {
    const float* W; bf16* Wt; int N; int tb = b;
    if (tb < 1024)      { W = W_zr1; Wt = wt_zr1; N = 2048; }
    else if (tb < 1536) { W = W_g1;  Wt = wt_g1;  N = 1024; tb -= 1024; }
    else if (tb < 2560) { W = W_zr2; Wt = wt_zr2; N = 2048; tb -= 1536; }
    else                { W = W_g2;  Wt = wt_g2;  N = 1024; tb -= 2560; }
    int ntn = N >> 6;
    int k0 = (tb / ntn) * 64, n0 = (tb % ntn) * 64;
    __shared__ float tile[64][65];
    int kk = t >> 4, nn = (t & 15) * 4;
#pragma unroll
    for (int s = 0; s < 4; ++s) {
      int row = kk + s * 16;
      float4 v = *(const float4*)&W[(size_t)(k0 + row) * N + n0 + nn];
      tile[row][nn + 0] = v.x; tile[row][nn + 1] = v.y;
      tile[row][nn + 2] = v.z; tile[row][nn + 3] = v.w;
    }
    __syncthreads();
    int k8 = (t & 7) * 8;
#pragma unroll
    for (int s = 0; s < 2; ++s) {
      int nl = (t >> 3) + s * 32;
      bf16 vals[8];
#pragma unroll
      for (int u = 0; u < 8; ++u) vals[u] = __float2bfloat16(tile[k8 + u][nl]);
      *(short8*)&Wt[(size_t)(n0 + nl) * KTOT + k0 + k8] = *(short8*)vals;
    }
  } else {
    int idx = (b - 3072) * 256 + t;
    int i = idx * 4;
    float4 xv = *(const float4*)(x + i);
    xb[i + 0] = __float2bfloat16(xv.x);
    xb[i + 1] = __float2bfloat16(xv.y);
    xb[i + 2] = __float2bfloat16(xv.z);
    xb[i + 3] = __float2bfloat16(xv.w);
    int m = i >> 10, j = i & 1023;
    int4 hv = *(const int4*)(hidden + m * HSZ + GG + j);
    const float sc = 1.0f / 8388608.0f;   // 2^-23
    hf[i + 0] = __float2bfloat16((float)hv.x * sc);
    hf[i + 1] = __float2bfloat16((float)hv.y * sc);
    hf[i + 2] = __float2bfloat16((float)hv.z * sc);
    hf[i + 3] = __float2bfloat16((float)hv.w * sc);
    if (idx == 0) *accp = 0.0f;
  }
}

// ---------------- shared GEMM mainloop: C(BM x 128) += [Aleft|Aright] @ Bt^T
// LDS k-group XOR-swizzle: chunk (row, c) holds global kgroup c ^ ((row>>1)&3)
// applied on both the global_load_lds source and the ds_read offset, so each
// 16-lane ds_read_b128 group covers all 8 bank phases (conflict-free).
template<int BM, int MI>
__device__ __forceinline__ void gemm_mainloop(const bf16* __restrict__ Aleft,
                                              const bf16* __restrict__ Aright,
                                              const bf16* __restrict__ Bt,
                                              bf16* As, bf16* Bs,
                                              int m0, int n0, floatx4 (&acc)[MI][4]) {
  int t = threadIdx.x;
  int r = t >> 2;
  int c2 = (t & 3) ^ ((t >> 3) & 3);        // swizzled staging k-group
  int lane = t & 63;
  int q = lane >> 4, r16 = lane & 15;
  int w = t >> 6;
  int wm = w & 1, wn = w >> 1;
  int swz = q ^ ((r16 >> 1) & 3);           // swizzled read k-group

  const size_t arow0 = (size_t)(m0 + r) * IN_SZ;
  const size_t arow1 = (size_t)(m0 + r + 64) * IN_SZ;   // BM==128 only
  const size_t brow0 = (size_t)(n0 + r) * KTOT;
  const size_t brow1 = (size_t)(n0 + r + 64) * KTOT;
  bf16* lA0 = As + t * 8;
  bf16* lA1 = As + 64 * 32 + t * 8;
  bf16* lB0 = Bs + t * 8;
  bf16* lB1 = Bs + 64 * 32 + t * 8;
  const bf16* aRd = As + (wm * (BM / 2) + r16) * 32 + swz * 8;
  const bf16* bRd = Bs + (wn * 64 + r16) * 32 + swz * 8;

  for (int kb = 0; kb < KTOT / 32; ++kb) {
    int kt = kb * 32;
    const bf16* asrc; int kloc;
    if (kt < IN_SZ) { asrc = Aleft;  kloc = kt; }
    else            { asrc = Aright; kloc = kt - IN_SZ; }
    int ac = kloc + c2 * 8;
    async_ld16(lA0, asrc + arow0 + ac);
    if (BM == 128) async_ld16(lA1, asrc + arow1 + ac);
    int bc = kt + c2 * 8;
    async_ld16(lB0, Bt + brow0 + bc);
    async_ld16(lB1, Bt + brow1 + bc);
    __syncthreads();
    short8 af[MI], bfr[4];
#pragma unroll
    for (int i = 0; i < MI; ++i) af[i]  = *(const short8*)(const void*)(aRd + i * 16 * 32);
#pragma unroll
    for (int j = 0; j < 4; ++j)  bfr[j] = *(const short8*)(const void*)(bRd + j * 16 * 32);
#pragma unroll
    for (int i = 0; i < MI; ++i)
#pragma unroll
      for (int j = 0; j < 4; ++j)
        acc[i][j] = __builtin_amdgcn_mfma_f32_16x16x32_bf16(af[i], bfr[j], acc[i][j], 0, 0, 0);
    __syncthreads();
  }
}

// ---------------- zr stage (128x128): sigmoid; z -> zbuf(bf16) + bits; r -> r*h
__global__ void gemm_zr(const bf16* __restrict__ xb, const bf16* __restrict__ hfp,
                        const bf16* __restrict__ Bt, const float* __restrict__ bias,
                        bf16* __restrict__ zbuf, bf16* __restrict__ rh,
                        const int* __restrict__ slice_ptr, int use_slice,
                        float* __restrict__ accp) {
  __shared__ bf16 As[128 * 32];
  __shared__ bf16 Bs[128 * 32];
  floatx4 acc[4][4];
#pragma unroll
  for (int i = 0; i < 4; ++i)
#pragma unroll
    for (int j = 0; j < 4; ++j) acc[i][j] = (floatx4)0.0f;

  int m0 = blockIdx.y * 128, n0 = blockIdx.x * 128;
  gemm_mainloop<128, 4>(xb, hfp, Bt, As, Bs, m0, n0, acc);

  int t = threadIdx.x;
  int lane = t & 63, q = lane >> 4, r16 = lane & 15;
  int w = t >> 6, wm = w & 1, wn = w >> 1;
  int nmin = use_slice ? *slice_ptr : 0;
  float lsum = 0.0f;

#pragma unroll
  for (int i = 0; i < 4; ++i) {
    int mbase = m0 + wm * 64 + i * 16 + q * 4;
#pragma unroll
    for (int j = 0; j < 4; ++j) {
      int n = n0 + wn * 64 + j * 16 + r16;
      float bn = bias[n];
#pragma unroll
      for (int rr = 0; rr < 4; ++rr) {
        int m = mbase + rr;
        float v = acc[i][j][rr] + bn;
        float s = 1.0f / (1.0f + __expf(-v));
        if (n < GG) {
          float z = 0.875f * s + 0.125f;
          zbuf[(size_t)m * GG + n] = __float2bfloat16(z);
          if (n >= nmin) lsum += -__log2f(z);
        } else {
          int jc = n - GG;
          float hfl = __bfloat162float(hfp[(size_t)m * GG + jc]);
          rh[(size_t)m * GG + jc] = __float2bfloat16(s * hfl);
        }
      }
    }
  }
  __syncthreads();
  float* sf = (float*)As;
#pragma unroll
  for (int off = 32; off > 0; off >>= 1) lsum += __shfl_down(lsum, off, 64);
  if (lane == 0) sf[w] = lsum;
  __syncthreads();
  if (t == 0) atomicAdd(accp, sf[0] + sf[1] + sf[2] + sf[3]);
}

// ---------------- g stage (64x128): tanh + fixed-point update + outputs ----
__global__ void gemm_g(const bf16* __restrict__ xb, const bf16* __restrict__ rh,
                       const bf16* __restrict__ Bt, const float* __restrict__ bias,
                       const bf16* __restrict__ zbuf, const int* __restrict__ hidden,
                       int col_off,
                       float* __restrict__ out0, float* __restrict__ out1,
                       bf16* __restrict__ hf_out, int write_hf,
                       int write_bits, const float* __restrict__ accp,
                       const int* __restrict__ slice_ptr, float* __restrict__ out2) {
  __shared__ bf16 As[64 * 32];
  __shared__ bf16 Bs[128 * 32];
  floatx4 acc[2][4];
#pragma unroll
  for (int i = 0; i < 2; ++i)
#pragma unroll
    for (int j = 0; j < 4; ++j) acc[i][j] = (floatx4)0.0f;

  int m0 = blockIdx.y * 64, n0 = blockIdx.x * 128;
  gemm_mainloop<64, 2>(xb, rh, Bt, As, Bs, m0, n0, acc);

  int t = threadIdx.x;
  int lane = t & 63, q = lane >> 4, r16 = lane & 15;
  int w = t >> 6, wm = w & 1, wn = w >> 1;

#pragma unroll
  for (int i = 0; i < 2; ++i) {
    int mbase = m0 + wm * 32 + i * 16 + q * 4;
#pragma unroll
    for (int j = 0; j < 4; ++j) {
      int n = n0 + wn * 64 + j * 16 + r16;
      float bn = bias[n];
#pragma unroll
      for (int rr = 0; rr < 4; ++rr) {
        int m = mbase + rr;
        float v = acc[i][j][rr] + bn;
        float e = __expf(2.0f * v);
        float g = 1.0f - 2.0f / (e + 1.0f);          // tanh(v)
        float z = __bfloat162float(zbuf[(size_t)m * GG + n]);
        int zfix = (int)(z * 1024.0f);               // trunc (z > 0)
        if (zfix < 1) zfix = 1;
        long long h = hidden[(size_t)m * HSZ + col_off + n];
        long long hupd = (h * (long long)zfix) >> 10;      // floor div 2^10
        float t2 = (1.0f - z) * g * 8388608.0f;            // *2^23
        long long f2 = (long long)t2;                      // trunc toward zero
        int hnew = (int)(hupd + f2);
        size_t oidx = (size_t)m * HSZ + col_off + n;
        out0[oidx] = (float)hnew;
        float ofl = (float)hnew * (1.0f / 8388608.0f);
        out1[oidx] = ofl;
        if (write_hf) hf_out[(size_t)m * GG + n] = __float2bfloat16(ofl);
      }
    }
  }
  if (write_bits && blockIdx.x == 0 && blockIdx.y == 0 && t == 0) {
    *out2 = *accp + 32.0f * (float)(*slice_ptr) * (float)BATCH;
  }
}

extern "C" void kernel_launch(void* const* d_in, const int* in_sizes, int n_in,
                              void* d_out, int out_size, void* d_ws, size_t ws_size,
                              hipStream_t stream) {
  const float* x      = (const float*)d_in[0];
  const int*   hidden = (const int*)d_in[1];
  const float* W_zr1  = (const float*)d_in[2];
  const float* b_zr1  = (const float*)d_in[3];
  const float* W_g1   = (const float*)d_in[4];
  const float* b_g1   = (const float*)d_in[5];
  const float* W_zr2  = (const float*)d_in[6];
  const float* b_zr2  = (const float*)d_in[7];
  const float* W_g2   = (const float*)d_in[8];
  const float* b_g2   = (const float*)d_in[9];
  const int*   slice  = (const int*)d_in[10];

  char* ws = (char*)d_ws;
  size_t off = 0;
  auto alloc = [&](size_t bytes) -> void* {
    void* p = ws + off;
    off += (bytes + 255) & ~(size_t)255;
    return p;
  };
  bf16* xb     = (bf16*)alloc((size_t)BATCH * IN_SZ * 2);
  bf16* wt_zr1 = (bf16*)alloc((size_t)2048 * 2048 * 2);
  bf16* wt_g1  = (bf16*)alloc((size_t)1024 * 2048 * 2);
  bf16* wt_zr2 = (bf16*)alloc((size_t)2048 * 2048 * 2);
  bf16* wt_g2  = (bf16*)alloc((size_t)1024 * 2048 * 2);
  bf16* hf     = (bf16*)alloc((size_t)BATCH * GG * 2);
  bf16* rh     = (bf16*)alloc((size_t)BATCH * GG * 2);
  bf16* zbuf   = (bf16*)alloc((size_t)BATCH * GG * 2);
  float* accp  = (float*)alloc(256);

  float* out0 = (float*)d_out;
  float* out1 = out0 + (size_t)BATCH * HSZ;
  float* out2 = out0 + 2 * (size_t)BATCH * HSZ;

  prep_all<<<3072 + 8192, 256, 0, stream>>>(x, xb, hidden, hf, accp,
                                            W_zr1, W_g1, W_zr2, W_g2,
                                            wt_zr1, wt_g1, wt_zr2, wt_g2);

  // stage 1: zr1 = sigmoid([x|h2f] @ W_zr1 + b)
  gemm_zr<<<dim3(16, 64), 256, 0, stream>>>(xb, hf, wt_zr1, b_zr1, zbuf, rh, slice, 1, accp);
  // stage 2: g1 = tanh([x|r1*h2f] @ W_g1 + b); h1 update; writes h1_fl into hf
  gemm_g<<<dim3(8, 128), 256, 0, stream>>>(xb, rh, wt_g1, b_g1, zbuf, hidden, 0,
                                           out0, out1, hf, 1, 0, accp, slice, out2);
  // stage 3: zr2 = sigmoid([x|h1f] @ W_zr2 + b)
  gemm_zr<<<dim3(16, 64), 256, 0, stream>>>(xb, hf, wt_zr2, b_zr2, zbuf, rh, slice, 0, accp);
  // stage 4: g2 = tanh([x|r2*h1f] @ W_g2 + b); h2 update; writes optimal_bits
  gemm_g<<<dim3(8, 128), 256, 0, stream>>>(xb, rh, wt_g2, b_g2, zbuf, hidden, 1024,
                                           out0, out1, hf, 0, 1, accp, slice, out2);
}

// Round 3
// 560.932 us; speedup vs baseline: 1.1741x; 1.1486x over previous
//
#include <hip/hip_runtime.h>
#include <hip/hip_bf16.h>

#define BATCH   8192
#define IN_SZ   1024
#define HSZ     2048
#define GG      1024
#define KTOT    2048

typedef __hip_bfloat16 bf16;
typedef __attribute__((ext_vector_type(8))) short  short8;
typedef __attribute__((ext_vector_type(4))) float  floatx4;

typedef __attribute__((address_space(1))) const void gvoid_t;
typedef __attribute__((address_space(3))) void       lvoid_t;

__device__ __forceinline__ void async_ld16(void* lds, const void* g) {
  __builtin_amdgcn_global_load_lds((gvoid_t*)g, (lvoid_t*)lds, 16, 0, 0);
}

// ---------------- fused prep: x->bf16, h2->bf16 float, 4 weight transposes --
__global__ void prep_all(const float* __restrict__ x, bf16* __restrict__ xb,
                         const int* __restrict__ hidden, bf16* __restrict__ hf,
                         float* accp,
                         const float* __restrict__ W_zr1, const float* __restrict__ W_g1,
                         const float* __restrict__ W_zr2, const float* __restrict__ W_g2,
                         bf16* __restrict__ wt_zr1, bf16* __restrict__ wt_g1,
                         bf16* __restrict__ wt_zr2, bf16* __restrict__ wt_g2) {
  int b = blockIdx.x;
  int t = threadIdx.x;
  if (b < 3072) {
    const float* W; bf16* Wt; int N; int tb = b;
    if (tb < 1024)      { W = W_zr1; Wt = wt_zr1; N = 2048; }
    else if (tb < 1536) { W = W_g1;  Wt = wt_g1;  N = 1024; tb -= 1024; }
    else if (tb < 2560) { W = W_zr2; Wt = wt_zr2; N = 2048; tb -= 1536; }
    else                { W = W_g2;  Wt = wt_g2;  N = 1024; tb -= 2560; }
    int ntn = N >> 6;
    int k0 = (tb / ntn) * 64, n0 = (tb % ntn) * 64;
    __shared__ float tile[64][65];
    int kk = t >> 4, nn = (t & 15) * 4;
#pragma unroll
    for (int s = 0; s < 4; ++s) {
      int row = kk + s * 16;
      float4 v = *(const float4*)&W[(size_t)(k0 + row) * N + n0 + nn];
      tile[row][nn + 0] = v.x; tile[row][nn + 1] = v.y;
      tile[row][nn + 2] = v.z; tile[row][nn + 3] = v.w;
    }
    __syncthreads();
    int k8 = (t & 7) * 8;
#pragma unroll
    for (int s = 0; s < 2; ++s) {
      int nl = (t >> 3) + s * 32;
      bf16 vals[8];
#pragma unroll
      for (int u = 0; u < 8; ++u) vals[u] = __float2bfloat16(tile[k8 + u][nl]);
      *(short8*)&Wt[(size_t)(n0 + nl) * KTOT + k0 + k8] = *(short8*)vals;
    }
  } else {
    int idx = (b - 3072) * 256 + t;
    int i = idx * 4;
    float4 xv = *(const float4*)(x + i);
    xb[i + 0] = __float2bfloat16(xv.x);
    xb[i + 1] = __float2bfloat16(xv.y);
    xb[i + 2] = __float2bfloat16(xv.z);
    xb[i + 3] = __float2bfloat16(xv.w);
    int m = i >> 10, j = i & 1023;
    int4 hv = *(const int4*)(hidden + m * HSZ + GG + j);
    const float sc = 1.0f / 8388608.0f;   // 2^-23
    hf[i + 0] = __float2bfloat16((float)hv.x * sc);
    hf[i + 1] = __float2bfloat16((float)hv.y * sc);
    hf[i + 2] = __float2bfloat16((float)hv.z * sc);
    hf[i + 3] = __float2bfloat16((float)hv.w * sc);
    if (idx == 0) *accp = 0.0f;
  }
}

// ---------------- GEMM mainloop, BK=64: C(BM x BN) += [Aleft|Aright] @ Bt^T
// LDS row = 64 bf16 = 128 B = 8 chunks of 16 B. Chunk XOR-swizzle:
// physical chunk p of row r holds global k-chunk p ^ (r & 7); applied on both
// the global_load_lds source column and the ds_read_b128 offset, so every
// group of 8 consecutive lanes covers all 8 bank phases (conflict-free).
// BK=64 -> 32 K-iterations: half the vmcnt(0) barrier drains of BK=32.
template<int BM, int BN, int MI, int NJ>
__device__ __forceinline__ void gemm_mainloop(const bf16* __restrict__ Aleft,
                                              const bf16* __restrict__ Aright,
                                              const bf16* __restrict__ Bt,
                                              bf16* As, bf16* Bs,
                                              int m0, int n0, floatx4 (&acc)[MI][NJ]) {
  constexpr int ACALLS = BM / 32;     // 32 rows staged per 256-thread call
  constexpr int BCALLS = BN / 32;
  int t = threadIdx.x;
  int lane = t & 63;
  int w = t >> 6;
  int l3 = lane >> 3;                  // 0..7
  int gchunk = (lane & 7) ^ l3;        // swizzled global k-chunk
  int rbase = w * 8 + l3;              // staging row within a 32-row group
  int q = lane >> 4, r16 = lane & 15;
  int wm = w & 1, wn = w >> 1;

  size_t a_off[ACALLS], b_off[BCALLS];
  bf16 *lA[ACALLS], *lB[BCALLS];
#pragma unroll
  for (int s = 0; s < ACALLS; ++s) {
    a_off[s] = (size_t)(m0 + rbase + s * 32) * IN_SZ + gchunk * 8;
    lA[s] = As + (s * 32 + w * 8) * 64 + lane * 8;
  }
#pragma unroll
  for (int s = 0; s < BCALLS; ++s) {
    b_off[s] = (size_t)(n0 + rbase + s * 32) * KTOT + gchunk * 8;
    lB[s] = Bs + (s * 32 + w * 8) * 64 + lane * 8;
  }
  const bf16* aRdBase = As + (wm * (BM / 2) + r16) * 64;
  const bf16* bRdBase = Bs + (wn * (BN / 2) + r16) * 64;
  int pc[2];
  pc[0] = ((q) ^ (r16 & 7)) * 8;
  pc[1] = ((4 + q) ^ (r16 & 7)) * 8;

  for (int kb = 0; kb < KTOT / 64; ++kb) {
    int kt = kb * 64;
    const bf16* asrc; int kloc;
    if (kt < IN_SZ) { asrc = Aleft;  kloc = kt; }
    else            { asrc = Aright; kloc = kt - IN_SZ; }
#pragma unroll
    for (int s = 0; s < ACALLS; ++s) async_ld16(lA[s], asrc + a_off[s] + kloc);
#pragma unroll
    for (int s = 0; s < BCALLS; ++s) async_ld16(lB[s], Bt + b_off[s] + kt);
    __syncthreads();
#pragma unroll
    for (int kh = 0; kh < 2; ++kh) {
      short8 af[MI], bfr[NJ];
#pragma unroll
      for (int i = 0; i < MI; ++i)
        af[i]  = *(const short8*)(const void*)(aRdBase + i * 16 * 64 + pc[kh]);
#pragma unroll
      for (int j = 0; j < NJ; ++j)
        bfr[j] = *(const short8*)(const void*)(bRdBase + j * 16 * 64 + pc[kh]);
#pragma unroll
      for (int i = 0; i < MI; ++i)
#pragma unroll
        for (int j = 0; j < NJ; ++j)
          acc[i][j] = __builtin_amdgcn_mfma_f32_16x16x32_bf16(af[i], bfr[j], acc[i][j], 0, 0, 0);
    }
    __syncthreads();
  }
}

// ---------------- zr stage (128x128): sigmoid; z -> zbuf(bf16)+bits; r -> r*h
__global__ void __launch_bounds__(256, 4)
gemm_zr(const bf16* __restrict__ xb, const bf16* __restrict__ hfp,
        const bf16* __restrict__ Bt, const float* __restrict__ bias,
        bf16* __restrict__ zbuf, bf16* __restrict__ rh,
        const int* __restrict__ slice_ptr, int use_slice,
        float* __restrict__ accp) {
  __shared__ bf16 As[128 * 64];
  __shared__ bf16 Bs[128 * 64];
  floatx4 acc[4][4];
#pragma unroll
  for (int i = 0; i < 4; ++i)
#pragma unroll
    for (int j = 0; j < 4; ++j) acc[i][j] = (floatx4)0.0f;

  // XCD swizzle: same m-band -> same XCD (linear%8 preserved by %64 remap)
  int linear = blockIdx.y * gridDim.x + blockIdx.x;
  int m0 = (linear & 63) * 128, n0 = (linear >> 6) * 128;
  gemm_mainloop<128, 128, 4, 4>(xb, hfp, Bt, As, Bs, m0, n0, acc);

  int t = threadIdx.x;
  int lane = t & 63, q = lane >> 4, r16 = lane & 15;
  int w = t >> 6, wm = w & 1, wn = w >> 1;
  int nmin = use_slice ? *slice_ptr : 0;
  float lsum = 0.0f;

#pragma unroll
  for (int i = 0; i < 4; ++i) {
    int mbase = m0 + wm * 64 + i * 16 + q * 4;
#pragma unroll
    for (int j = 0; j < 4; ++j) {
      int n = n0 + wn * 64 + j * 16 + r16;
      float bn = bias[n];
#pragma unroll
      for (int rr = 0; rr < 4; ++rr) {
        int m = mbase + rr;
        float v = acc[i][j][rr] + bn;
        float s = 1.0f / (1.0f + __expf(-v));
        if (n < GG) {
          float z = 0.875f * s + 0.125f;
          zbuf[(size_t)m * GG + n] = __float2bfloat16(z);
          if (n >= nmin) lsum += -__log2f(z);
        } else {
          int jc = n - GG;
          float hfl = __bfloat162float(hfp[(size_t)m * GG + jc]);
          rh[(size_t)m * GG + jc] = __float2bfloat16(s * hfl);
        }
      }
    }
  }
  __syncthreads();
  float* sf = (float*)As;
#pragma unroll
  for (int off = 32; off > 0; off >>= 1) lsum += __shfl_down(lsum, off, 64);
  if (lane == 0) sf[w] = lsum;
  __syncthreads();
  if (t == 0) atomicAdd(accp, sf[0] + sf[1] + sf[2] + sf[3]);
}

// ---------------- g stage (128x64): tanh + fixed-point update + outputs ----
__global__ void __launch_bounds__(256, 4)
gemm_g(const bf16* __restrict__ xb, const bf16* __restrict__ rh,
       const bf16* __restrict__ Bt, const float* __restrict__ bias,
       const bf16* __restrict__ zbuf, const int* __restrict__ hidden,
       int col_off,
       float* __restrict__ out0, float* __restrict__ out1,
       bf16* __restrict__ hf_out, int write_hf,
       int write_bits, const float* __restrict__ accp,
       const int* __restrict__ slice_ptr, float* __restrict__ out2) {
  __shared__ bf16 As[128 * 64];
  __shared__ bf16 Bs[64 * 64];
  floatx4 acc[4][2];
#pragma unroll
  for (int i = 0; i < 4; ++i)
#pragma unroll
    for (int j = 0; j < 2; ++j) acc[i][j] = (floatx4)0.0f;

  int linear = blockIdx.y * gridDim.x + blockIdx.x;
  int m0 = (linear & 63) * 128, n0 = (linear >> 6) * 64;
  gemm_mainloop<128, 64, 4, 2>(xb, rh, Bt, As, Bs, m0, n0, acc);

  int t = threadIdx.x;
  int lane = t & 63, q = lane >> 4, r16 = lane & 15;
  int w = t >> 6, wm = w & 1, wn = w >> 1;

#pragma unroll
  for (int i = 0; i < 4; ++i) {
    int mbase = m0 + wm * 64 + i * 16 + q * 4;
#pragma unroll
    for (int j = 0; j < 2; ++j) {
      int n = n0 + wn * 32 + j * 16 + r16;
      float bn = bias[n];
#pragma unroll
      for (int rr = 0; rr < 4; ++rr) {
        int m = mbase + rr;
        float v = acc[i][j][rr] + bn;
        float e = __expf(2.0f * v);
        float g = 1.0f - 2.0f / (e + 1.0f);          // tanh(v)
        float z = __bfloat162float(zbuf[(size_t)m * GG + n]);
        int zfix = (int)(z * 1024.0f);               // trunc (z > 0)
        if (zfix < 1) zfix = 1;
        long long h = hidden[(size_t)m * HSZ + col_off + n];
        long long hupd = (h * (long long)zfix) >> 10;      // floor div 2^10
        float t2 = (1.0f - z) * g * 8388608.0f;            // *2^23
        long long f2 = (long long)t2;                      // trunc toward zero
        int hnew = (int)(hupd + f2);
        size_t oidx = (size_t)m * HSZ + col_off + n;
        out0[oidx] = (float)hnew;
        float ofl = (float)hnew * (1.0f / 8388608.0f);
        out1[oidx] = ofl;
        if (write_hf) hf_out[(size_t)m * GG + n] = __float2bfloat16(ofl);
      }
    }
  }
  if (write_bits && blockIdx.x == 0 && blockIdx.y == 0 && t == 0) {
    *out2 = *accp + 32.0f * (float)(*slice_ptr) * (float)BATCH;
  }
}

extern "C" void kernel_launch(void* const* d_in, const int* in_sizes, int n_in,
                              void* d_out, int out_size, void* d_ws, size_t ws_size,
                              hipStream_t stream) {
  const float* x      = (const float*)d_in[0];
  const int*   hidden = (const int*)d_in[1];
  const float* W_zr1  = (const float*)d_in[2];
  const float* b_zr1  = (const float*)d_in[3];
  const float* W_g1   = (const float*)d_in[4];
  const float* b_g1   = (const float*)d_in[5];
  const float* W_zr2  = (const float*)d_in[6];
  const float* b_zr2  = (const float*)d_in[7];
  const float* W_g2   = (const float*)d_in[8];
  const float* b_g2   = (const float*)d_in[9];
  const int*   slice  = (const int*)d_in[10];

  char* ws = (char*)d_ws;
  size_t off = 0;
  auto alloc = [&](size_t bytes) -> void* {
    void* p = ws + off;
    off += (bytes + 255) & ~(size_t)255;
    return p;
  };
  bf16* xb     = (bf16*)alloc((size_t)BATCH * IN_SZ * 2);
  bf16* wt_zr1 = (bf16*)alloc((size_t)2048 * 2048 * 2);
  bf16* wt_g1  = (bf16*)alloc((size_t)1024 * 2048 * 2);
  bf16* wt_zr2 = (bf16*)alloc((size_t)2048 * 2048 * 2);
  bf16* wt_g2  = (bf16*)alloc((size_t)1024 * 2048 * 2);
  bf16* hf     = (bf16*)alloc((size_t)BATCH * GG * 2);
  bf16* rh     = (bf16*)alloc((size_t)BATCH * GG * 2);
  bf16* zbuf   = (bf16*)alloc((size_t)BATCH * GG * 2);
  float* accp  = (float*)alloc(256);

  float* out0 = (float*)d_out;
  float* out1 = out0 + (size_t)BATCH * HSZ;
  float* out2 = out0 + 2 * (size_t)BATCH * HSZ;

  prep_all<<<3072 + 8192, 256, 0, stream>>>(x, xb, hidden, hf, accp,
                                            W_zr1, W_g1, W_zr2, W_g2,
                                            wt_zr1, wt_g1, wt_zr2, wt_g2);

  // stage 1: zr1 = sigmoid([x|h2f] @ W_zr1 + b)
  gemm_zr<<<dim3(16, 64), 256, 0, stream>>>(xb, hf, wt_zr1, b_zr1, zbuf, rh, slice, 1, accp);
  // stage 2: g1 = tanh([x|r1*h2f] @ W_g1 + b); h1 update; writes h1_fl into hf
  gemm_g<<<dim3(16, 64), 256, 0, stream>>>(xb, rh, wt_g1, b_g1, zbuf, hidden, 0,
                                           out0, out1, hf, 1, 0, accp, slice, out2);
  // stage 3: zr2 = sigmoid([x|h1f] @ W_zr2 + b)
  gemm_zr<<<dim3(16, 64), 256, 0, stream>>>(xb, hf, wt_zr2, b_zr2, zbuf, rh, slice, 0, accp);
  // stage 4: g2 = tanh([x|r2*h1f] @ W_g2 + b); h2 update; writes optimal_bits
  gemm_g<<<dim3(16, 64), 256, 0, stream>>>(xb, rh, wt_g2, b_g2, zbuf, hidden, 1024,
                                           out0, out1, hf, 0, 1, accp, slice, out2);
}